// Round 10
// baseline (570.753 us; speedup 1.0000x reference)
//
#include <hip/hip_runtime.h>
#include <stdint.h>

#define HID 1024
#define HEADS 16
#define HDIM 64
#define SEQ 2048
#define BATCH 4
#define SCALE 0.125f
// exp(x*SCALE) = exp2(x * SCALE*log2(e)); folded into Q-projection epilogue
#define EXPC 0.18033688011112042f

typedef __bf16 bf16x8 __attribute__((ext_vector_type(8)));
typedef float f32x4 __attribute__((ext_vector_type(4)));
typedef unsigned short ushortx8 __attribute__((ext_vector_type(8)));
typedef unsigned short ushortx4 __attribute__((ext_vector_type(4)));

__device__ __forceinline__ unsigned short f2bf(float f) {
  uint32_t u = __builtin_bit_cast(uint32_t, f);
  u = (u + 0x7fffu + ((u >> 16) & 1u)) >> 16;
  return (unsigned short)u;
}
__device__ __forceinline__ float bf2f(unsigned short u) {
  uint32_t x = ((uint32_t)u) << 16;
  return __builtin_bit_cast(float, x);
}
__device__ __forceinline__ void gl16(const void* g, void* l) {
  __builtin_amdgcn_global_load_lds(
      (const __attribute__((address_space(1))) unsigned int*)g,
      (__attribute__((address_space(3))) unsigned int*)l, 16, 0, 0);
}

// ---------------- fp32 -> bf16 pre-convert (weights only) ----------------
struct ConvArgs {
  const float* s[4];
  unsigned short* d[4];
  int n[4];
};
__global__ __launch_bounds__(256) void convk(ConvArgs a) {
  const int ten = blockIdx.y;
  const float* s = a.s[ten];
  unsigned short* d = a.d[ten];
  const int n = a.n[ten];
  const int stride = gridDim.x * blockDim.x * 8;
  for (int i = (blockIdx.x * blockDim.x + threadIdx.x) * 8; i < n; i += stride) {
    float4 v0 = *(const float4*)(s + i);
    float4 v1 = *(const float4*)(s + i + 4);
    ushortx8 o = {f2bf(v0.x), f2bf(v0.y), f2bf(v0.z), f2bf(v0.w),
                  f2bf(v1.x), f2bf(v1.y), f2bf(v1.z), f2bf(v1.w)};
    *(ushortx8*)(d + i) = o;
  }
}

// ---------------- merged Q/K/V projection GEMM ----------------
// A fp32 (fused convert in staging), W bf16 via global_load_lds.
// z==0: out scaled by EXPC (Q feeds only scores). z==2: V transposed [B,H,D,S].
// Flat grid 1536, XCD-chunked swizzle (each XCD: contiguous 192 wgids).
struct QkvArgs {
  const float* Af[3];
  const unsigned short* W[3];
  const float* bias[3];
  unsigned short* out[3];
};
__global__ __launch_bounds__(256) void gemm_qkv(QkvArgs ar) {
  __shared__ unsigned short Als[128 * 64];
  __shared__ unsigned short Bls[128 * 64];
  const int bid = blockIdx.x;
  const int wgid = (bid & 7) * 192 + (bid >> 3);
  const int z = wgid >> 9;
  const int rem = wgid & 511;
  const int bm = rem >> 3, bn = rem & 7;

  const float* Af = ar.Af[z];
  const unsigned short* Wb = ar.W[z];
  const float* bias = ar.bias[z];
  unsigned short* Out = ar.out[z];

  const int t = threadIdx.x;
  const int w = t >> 6, lane = t & 63;
  const int wm = w >> 1, wn = w & 1;
  const int lr = lane & 15, lk = lane >> 4;
  const int row0 = bm * 128, col0 = bn * 128;

  const unsigned short* Wbase =
      Wb + (size_t)(col0 + w * 32 + (lane >> 3)) * HID + (lane & 7) * 8;

  f32x4 acc[4][4] = {};

  for (int ks = 0; ks < 16; ++ks) {
    __syncthreads();
#pragma unroll
    for (int i = 0; i < 4; ++i)
      gl16(Wbase + (size_t)i * 8 * HID + ks * 64, &Bls[(w * 32 + i * 8) * 64]);
#pragma unroll
    for (int i = 0; i < 8; ++i) {
      int chunk = t + i * 256;
      int r = chunk >> 4, c4 = (chunk & 15) * 4;
      float4 v4 = *(const float4*)(Af + (size_t)(row0 + r) * HID + ks * 64 + c4);
      ushortx4 o = {f2bf(v4.x), f2bf(v4.y), f2bf(v4.z), f2bf(v4.w)};
      *(ushortx4*)&Als[r * 64 + c4] = o;
    }
    __syncthreads();
#pragma unroll
    for (int kk = 0; kk < 2; ++kk) {
      bf16x8 a[4], bb[4];
#pragma unroll
      for (int f = 0; f < 4; ++f) {
        a[f] = *(const bf16x8*)&Als[(wm * 64 + f * 16 + lr) * 64 + kk * 32 + lk * 8];
        bb[f] = *(const bf16x8*)&Bls[(wn * 64 + f * 16 + lr) * 64 + kk * 32 + lk * 8];
      }
#pragma unroll
      for (int fm = 0; fm < 4; ++fm)
#pragma unroll
        for (int fn = 0; fn < 4; ++fn)
          acc[fm][fn] = __builtin_amdgcn_mfma_f32_16x16x32_bf16(
              a[fm], bb[fn], acc[fm][fn], 0, 0, 0);
    }
  }

  const float sc = (z == 0) ? EXPC : 1.0f;
#pragma unroll
  for (int fn = 0; fn < 4; ++fn) {
    int col = col0 + wn * 64 + fn * 16 + lr;
    float bv = bias[col];
#pragma unroll
    for (int fm = 0; fm < 4; ++fm) {
      int row = row0 + wm * 64 + fm * 16 + lk * 4;
      if (z == 2) {
        int b_ = row >> 11, s = row & 2047;
        int hh = col >> 6, d = col & 63;
        ushortx4 o4 = {f2bf(acc[fm][fn][0] + bv), f2bf(acc[fm][fn][1] + bv),
                       f2bf(acc[fm][fn][2] + bv), f2bf(acc[fm][fn][3] + bv)};
        *(ushortx4*)(Out + ((size_t)(b_ * HEADS + hh) * HDIM + d) * SEQ + s) = o4;
      } else {
#pragma unroll
        for (int r = 0; r < 4; ++r)
          Out[(size_t)(row + r) * HID + col] = f2bf((acc[fm][fn][r] + bv) * sc);
      }
    }
  }
}

// ---------------- Wo GEMM ----------------
// Flat grid 512, XCD-chunked swizzle. W_F32: fp32 W fallback.
template <int W_F32>
__global__ __launch_bounds__(256) void gemm_wo(
    const unsigned short* __restrict__ A, const void* __restrict__ Wp,
    const float* __restrict__ bias, float* __restrict__ Out) {
  __shared__ unsigned short Als[128 * 64];
  __shared__ unsigned short Bls[128 * 64];
  const int bid = blockIdx.x;
  const int wgid = (bid & 7) * 64 + (bid >> 3);
  const int bm = wgid >> 3, bn = wgid & 7;
  const int t = threadIdx.x;
  const int w = t >> 6, lane = t & 63;
  const int wm = w >> 1, wn = w & 1;
  const int lr = lane & 15, lk = lane >> 4;
  const int row0 = bm * 128, col0 = bn * 128;

  const unsigned short* Abase =
      A + (size_t)(row0 + w * 32 + (lane >> 3)) * HID + (lane & 7) * 8;
  const unsigned short* Wb16 =
      (const unsigned short*)Wp + (size_t)(col0 + w * 32 + (lane >> 3)) * HID +
      (lane & 7) * 8;

  f32x4 acc[4][4] = {};

  for (int ks = 0; ks < 16; ++ks) {
    __syncthreads();
#pragma unroll
    for (int i = 0; i < 4; ++i)
      gl16(Abase + (size_t)i * 8 * HID + ks * 64, &Als[(w * 32 + i * 8) * 64]);
    if (!W_F32) {
#pragma unroll
      for (int i = 0; i < 4; ++i)
        gl16(Wb16 + (size_t)i * 8 * HID + ks * 64, &Bls[(w * 32 + i * 8) * 64]);
    } else {
      const float* Wf = (const float*)Wp;
#pragma unroll
      for (int i = 0; i < 8; ++i) {
        int chunk = t + i * 256;
        int r = chunk >> 4, c4 = (chunk & 15) * 4;
        float4 v4 = *(const float4*)(Wf + (size_t)(col0 + r) * HID + ks * 64 + c4);
        ushortx4 o = {f2bf(v4.x), f2bf(v4.y), f2bf(v4.z), f2bf(v4.w)};
        *(ushortx4*)&Bls[r * 64 + c4] = o;
      }
    }
    __syncthreads();
#pragma unroll
    for (int kk = 0; kk < 2; ++kk) {
      bf16x8 a[4], bb[4];
#pragma unroll
      for (int f = 0; f < 4; ++f) {
        a[f] = *(const bf16x8*)&Als[(wm * 64 + f * 16 + lr) * 64 + kk * 32 + lk * 8];
        bb[f] = *(const bf16x8*)&Bls[(wn * 64 + f * 16 + lr) * 64 + kk * 32 + lk * 8];
      }
#pragma unroll
      for (int fm = 0; fm < 4; ++fm)
#pragma unroll
        for (int fn = 0; fn < 4; ++fn)
          acc[fm][fn] = __builtin_amdgcn_mfma_f32_16x16x32_bf16(
              a[fm], bb[fn], acc[fm][fn], 0, 0, 0);
    }
  }

#pragma unroll
  for (int fn = 0; fn < 4; ++fn) {
    int col = col0 + wn * 64 + fn * 16 + lr;
    float bv = bias[col];
#pragma unroll
    for (int fm = 0; fm < 4; ++fm) {
      int row = row0 + wm * 64 + fm * 16 + lk * 4;
#pragma unroll
      for (int r = 0; r < 4; ++r)
        Out[(size_t)(row + r) * HID + col] = acc[fm][fn][r] + bv;
    }
  }
}

// ---------------- attention ----------------
// R6 structure (402 us) + occupancy pin. Flat grid 512, XCD-chunked swizzle;
// each block does 2 q-blocks of 128 rows sequentially (same h,b). Two-pass
// per q-block, no max-tracking; Q pre-scaled by EXPC. K/V via global_load_lds,
// XOR-swizzled via source, double-buffered, one barrier per tile.
// __launch_bounds__(512,4): 4 waves/EU -> VGPR<=128 -> 2 blocks/CU resident.
__global__ __launch_bounds__(512, 4) void attn_kern(
    const unsigned short* __restrict__ Qb, const unsigned short* __restrict__ Kb,
    const unsigned short* __restrict__ Vt, float* __restrict__ attn_out,
    unsigned short* __restrict__ Xc) {
  __shared__ unsigned short Qls[128][72];  // reused as P (bf16) in pass 2
  __shared__ unsigned short Kls[2][64 * 64];
  __shared__ unsigned short Vls[2][64 * 64];

  const int t = threadIdx.x;
  const int bid = blockIdx.x;
  const int wgid = (bid & 7) * 64 + (bid >> 3);
  const int qbp = wgid & 7;
  const int h = (wgid >> 3) & 15;
  const int b = wgid >> 7;

  const int w = t >> 6, lane = t & 63;
  const int lr = lane & 15, lk = lane >> 4;

  const int srow = lane >> 3;
  const int scol = (lane & 7) ^ srow;
  const unsigned short* gK =
      Kb + ((size_t)b * SEQ + w * 8 + srow) * HID + h * HDIM + scol * 8;
  const unsigned short* gV =
      Vt + ((size_t)(b * HEADS + h) * HDIM + w * 8 + srow) * SEQ + scol * 8;
  unsigned short* lK = &Kls[0][w * 8 * 64];  // +4096 for buf 1
  unsigned short* lV = &Vls[0][w * 8 * 64];

  for (int qbi = 0; qbi < 2; ++qbi) {
    const int qb = qbp * 2 + qbi;
    const size_t qrow0 = (size_t)b * SEQ + (size_t)qb * 128;

    // issue K tile 0 while staging Q
    gl16(gK, lK);
#pragma unroll
    for (int i = 0; i < 2; ++i) {
      int chunk = t + i * 512;
      int r = chunk >> 3, c8 = (chunk & 7) * 8;
      *(ushortx8*)&Qls[r][c8] =
          *(const ushortx8*)(Qb + (qrow0 + r) * HID + h * HDIM + c8);
    }
    __syncthreads();  // Q visible, K tile0 staged

    bf16x8 qf[2];
#pragma unroll
    for (int kk = 0; kk < 2; ++kk)
      qf[kk] = *(const bf16x8*)&Qls[w * 16 + lr][kk * 32 + lk * 8];
    auto& Pls = Qls;

    float lsum[4] = {0.f, 0.f, 0.f, 0.f};
    int buf = 0;

    // ---- pass 1: row sums of exp2 ----
    for (int kt = 0; kt < 32; ++kt) {
      if (kt < 31) gl16(gK + (size_t)(kt + 1) * 64 * HID, lK + (buf ^ 1) * 4096);
      f32x4 acc[4] = {};
      __builtin_amdgcn_s_setprio(1);
#pragma unroll
      for (int kk = 0; kk < 2; ++kk)
#pragma unroll
        for (int kf = 0; kf < 4; ++kf) {
          bf16x8 bb = *(const bf16x8*)&Kls[buf][(kf * 16 + lr) * 64 +
                                               (((kk * 4 + lk) ^ (lr & 7)) << 3)];
          acc[kf] =
              __builtin_amdgcn_mfma_f32_16x16x32_bf16(qf[kk], bb, acc[kf], 0, 0, 0);
        }
      __builtin_amdgcn_s_setprio(0);
#pragma unroll
      for (int kf = 0; kf < 4; ++kf)
#pragma unroll
        for (int r = 0; r < 4; ++r) lsum[r] += exp2f(acc[kf][r]);
      __syncthreads();
      buf ^= 1;
    }

    float invl[4];
#pragma unroll
    for (int r = 0; r < 4; ++r) {
#pragma unroll
      for (int off = 1; off < 16; off <<= 1) lsum[r] += __shfl_xor(lsum[r], off, 64);
      invl[r] = 1.0f / lsum[r];
    }

    f32x4 oacc[4] = {};
    float* attn_base =
        attn_out + ((size_t)(b * HEADS + h) * SEQ + (size_t)qb * 128) * SEQ;

    // ---- pass 2 ---- (buf is 0 again)
    gl16(gK, lK);
    gl16(gV, lV);
    __syncthreads();
    for (int kt = 0; kt < 32; ++kt) {
      if (kt < 31) {
        gl16(gK + (size_t)(kt + 1) * 64 * HID, lK + (buf ^ 1) * 4096);
        gl16(gV + (size_t)(kt + 1) * 64, lV + (buf ^ 1) * 4096);
      }
      f32x4 acc[4] = {};
      __builtin_amdgcn_s_setprio(1);
#pragma unroll
      for (int kk = 0; kk < 2; ++kk)
#pragma unroll
        for (int kf = 0; kf < 4; ++kf) {
          bf16x8 bb = *(const bf16x8*)&Kls[buf][(kf * 16 + lr) * 64 +
                                               (((kk * 4 + lk) ^ (lr & 7)) << 3)];
          acc[kf] =
              __builtin_amdgcn_mfma_f32_16x16x32_bf16(qf[kk], bb, acc[kf], 0, 0, 0);
        }
      __builtin_amdgcn_s_setprio(0);
      // normalized P -> LDS (bf16); rows are wave-local
#pragma unroll
      for (int kf = 0; kf < 4; ++kf)
#pragma unroll
        for (int r = 0; r < 4; ++r) {
          float p = exp2f(acc[kf][r]) * invl[r];
          Pls[w * 16 + lk * 4 + r][kf * 16 + lr] = f2bf(p);
        }
      // coalesced fp32 attention write (nontemporal; b128 LDS reads)
#pragma unroll
      for (int it = 0; it < 2; ++it) {
        int rl = it * 8 + (lane >> 3);
        int c8 = lane & 7;
        ushortx8 p8 = *(const ushortx8*)&Pls[w * 16 + rl][c8 * 8];
        f32x4 o0 = {bf2f(p8[0]), bf2f(p8[1]), bf2f(p8[2]), bf2f(p8[3])};
        f32x4 o1 = {bf2f(p8[4]), bf2f(p8[5]), bf2f(p8[6]), bf2f(p8[7])};
        float* dst = attn_base + (size_t)(w * 16 + rl) * SEQ + kt * 64 + c8 * 8;
        __builtin_nontemporal_store(o0, (f32x4*)dst);
        __builtin_nontemporal_store(o1, (f32x4*)(dst + 4));
      }
      // PV accumulate
      __builtin_amdgcn_s_setprio(1);
#pragma unroll
      for (int kk = 0; kk < 2; ++kk) {
        bf16x8 ap = *(const bf16x8*)&Pls[w * 16 + lr][kk * 32 + lk * 8];
#pragma unroll
        for (int df = 0; df < 4; ++df) {
          bf16x8 bv = *(const bf16x8*)&Vls[buf][(df * 16 + lr) * 64 +
                                               (((kk * 4 + lk) ^ (lr & 7)) << 3)];
          oacc[df] =
              __builtin_amdgcn_mfma_f32_16x16x32_bf16(ap, bv, oacc[df], 0, 0, 0);
        }
      }
      __builtin_amdgcn_s_setprio(0);
      __syncthreads();
      buf ^= 1;
    }

#pragma unroll
    for (int df = 0; df < 4; ++df)
#pragma unroll
      for (int r = 0; r < 4; ++r) {
        int row = w * 16 + lk * 4 + r;
        int col = h * HDIM + df * 16 + lr;
        Xc[(qrow0 + row) * HID + col] = f2bf(oacc[df][r]);
      }
  }
}

extern "C" void kernel_launch(void* const* d_in, const int* in_sizes, int n_in,
                              void* d_out, int out_size, void* d_ws, size_t ws_size,
                              hipStream_t stream) {
  const float* q = (const float*)d_in[0];
  const float* k = (const float*)d_in[1];
  const float* v = (const float*)d_in[2];
  const float* Wq = (const float*)d_in[3];
  const float* bq = (const float*)d_in[4];
  const float* Wk = (const float*)d_in[5];
  const float* bk = (const float*)d_in[6];
  const float* Wv = (const float*)d_in[7];
  const float* bv = (const float*)d_in[8];
  const float* Wo = (const float*)d_in[9];
  const float* bo = (const float*)d_in[10];

  char* ws = (char*)d_ws;
  const size_t MAT = (size_t)8192 * 1024 * sizeof(unsigned short);  // 16 MiB
  unsigned short* Qbuf = (unsigned short*)(ws);
  unsigned short* Kbuf = (unsigned short*)(ws + MAT);
  unsigned short* Vtb = (unsigned short*)(ws + 2 * MAT);
  unsigned short* Xc = (unsigned short*)(ws + 3 * MAT);

  float* xout = (float*)d_out;
  float* attn_out = xout + (size_t)BATCH * SEQ * HID;

  // bf16 weight copies for Wq/Wk/Wv live in the attn region of d_out
  // (fully overwritten later by attn_kern; consumed before that).
  unsigned short* scr = (unsigned short*)attn_out;
  const int NW = 1024 * 1024;
  unsigned short* wq16 = scr;
  unsigned short* wk16 = wq16 + NW;
  unsigned short* wv16 = wk16 + NW;
  // Wo bf16 copy must survive attn -> lives in ws (guarded by ws_size)
  unsigned short* wo16 = (unsigned short*)(ws + 4 * MAT);
  const bool wo_bf = ws_size >= 4 * MAT + (size_t)NW * sizeof(unsigned short);

  ConvArgs ca;
  ca.s[0] = Wq; ca.s[1] = Wk; ca.s[2] = Wv; ca.s[3] = Wo;
  ca.d[0] = wq16; ca.d[1] = wk16; ca.d[2] = wv16; ca.d[3] = wo16;
  ca.n[0] = NW; ca.n[1] = NW; ca.n[2] = NW; ca.n[3] = NW;

  dim3 blk(256);
  hipLaunchKernelGGL(convk, dim3(128, wo_bf ? 4 : 3), blk, 0, stream, ca);

  QkvArgs qa;
  qa.Af[0] = q; qa.Af[1] = k; qa.Af[2] = v;
  qa.W[0] = wq16; qa.W[1] = wk16; qa.W[2] = wv16;
  qa.bias[0] = bq; qa.bias[1] = bk; qa.bias[2] = bv;
  qa.out[0] = Qbuf; qa.out[1] = Kbuf; qa.out[2] = Vtb;
  hipLaunchKernelGGL(gemm_qkv, dim3(1536), blk, 0, stream, qa);

  hipLaunchKernelGGL(attn_kern, dim3(512), dim3(512), 0, stream, Qbuf, Kbuf, Vtb,
                     attn_out, Xc);

  if (wo_bf)
    hipLaunchKernelGGL((gemm_wo<0>), dim3(512), blk, 0, stream, Xc, wo16, bo, xout);
  else
    hipLaunchKernelGGL((gemm_wo<1>), dim3(512), blk, 0, stream, Xc, Wo, bo, xout);
}

// Round 11
// 399.025 us; speedup vs baseline: 1.4304x; 1.4304x over previous
//
#include <hip/hip_runtime.h>
#include <stdint.h>

#define HID 1024
#define HEADS 16
#define HDIM 64
#define SEQ 2048
#define BATCH 4
#define SCALE 0.125f
// exp(x*SCALE) = exp2(x * SCALE*log2(e)); folded into Q-projection epilogue
#define EXPC 0.18033688011112042f

typedef __bf16 bf16x8 __attribute__((ext_vector_type(8)));
typedef float f32x4 __attribute__((ext_vector_type(4)));
typedef unsigned short ushortx8 __attribute__((ext_vector_type(8)));
typedef unsigned short ushortx4 __attribute__((ext_vector_type(4)));

__device__ __forceinline__ unsigned short f2bf(float f) {
  uint32_t u = __builtin_bit_cast(uint32_t, f);
  u = (u + 0x7fffu + ((u >> 16) & 1u)) >> 16;
  return (unsigned short)u;
}
__device__ __forceinline__ float bf2f(unsigned short u) {
  uint32_t x = ((uint32_t)u) << 16;
  return __builtin_bit_cast(float, x);
}
__device__ __forceinline__ void gl16(const void* g, void* l) {
  __builtin_amdgcn_global_load_lds(
      (const __attribute__((address_space(1))) unsigned int*)g,
      (__attribute__((address_space(3))) unsigned int*)l, 16, 0, 0);
}

// ---------------- fp32 -> bf16 pre-convert (weights only) ----------------
struct ConvArgs {
  const float* s[4];
  unsigned short* d[4];
  int n[4];
};
__global__ __launch_bounds__(256) void convk(ConvArgs a) {
  const int ten = blockIdx.y;
  const float* s = a.s[ten];
  unsigned short* d = a.d[ten];
  const int n = a.n[ten];
  const int stride = gridDim.x * blockDim.x * 8;
  for (int i = (blockIdx.x * blockDim.x + threadIdx.x) * 8; i < n; i += stride) {
    float4 v0 = *(const float4*)(s + i);
    float4 v1 = *(const float4*)(s + i + 4);
    ushortx8 o = {f2bf(v0.x), f2bf(v0.y), f2bf(v0.z), f2bf(v0.w),
                  f2bf(v1.x), f2bf(v1.y), f2bf(v1.z), f2bf(v1.w)};
    *(ushortx8*)(d + i) = o;
  }
}

// ---------------- merged Q/K/V projection GEMM ----------------
// A fp32 (fused convert in staging), W bf16 via global_load_lds.
// z==0: out scaled by EXPC (Q feeds only scores). z==2: V transposed [B,H,D,S].
// Flat grid 1536, XCD-chunked swizzle (each XCD: contiguous 192 wgids).
struct QkvArgs {
  const float* Af[3];
  const unsigned short* W[3];
  const float* bias[3];
  unsigned short* out[3];
};
__global__ __launch_bounds__(256) void gemm_qkv(QkvArgs ar) {
  __shared__ unsigned short Als[128 * 64];
  __shared__ unsigned short Bls[128 * 64];
  const int bid = blockIdx.x;
  const int wgid = (bid & 7) * 192 + (bid >> 3);
  const int z = wgid >> 9;
  const int rem = wgid & 511;
  const int bm = rem >> 3, bn = rem & 7;

  const float* Af = ar.Af[z];
  const unsigned short* Wb = ar.W[z];
  const float* bias = ar.bias[z];
  unsigned short* Out = ar.out[z];

  const int t = threadIdx.x;
  const int w = t >> 6, lane = t & 63;
  const int wm = w >> 1, wn = w & 1;
  const int lr = lane & 15, lk = lane >> 4;
  const int row0 = bm * 128, col0 = bn * 128;

  const unsigned short* Wbase =
      Wb + (size_t)(col0 + w * 32 + (lane >> 3)) * HID + (lane & 7) * 8;

  f32x4 acc[4][4] = {};

  for (int ks = 0; ks < 16; ++ks) {
    __syncthreads();
#pragma unroll
    for (int i = 0; i < 4; ++i)
      gl16(Wbase + (size_t)i * 8 * HID + ks * 64, &Bls[(w * 32 + i * 8) * 64]);
#pragma unroll
    for (int i = 0; i < 8; ++i) {
      int chunk = t + i * 256;
      int r = chunk >> 4, c4 = (chunk & 15) * 4;
      float4 v4 = *(const float4*)(Af + (size_t)(row0 + r) * HID + ks * 64 + c4);
      ushortx4 o = {f2bf(v4.x), f2bf(v4.y), f2bf(v4.z), f2bf(v4.w)};
      *(ushortx4*)&Als[r * 64 + c4] = o;
    }
    __syncthreads();
#pragma unroll
    for (int kk = 0; kk < 2; ++kk) {
      bf16x8 a[4], bb[4];
#pragma unroll
      for (int f = 0; f < 4; ++f) {
        a[f] = *(const bf16x8*)&Als[(wm * 64 + f * 16 + lr) * 64 + kk * 32 + lk * 8];
        bb[f] = *(const bf16x8*)&Bls[(wn * 64 + f * 16 + lr) * 64 + kk * 32 + lk * 8];
      }
#pragma unroll
      for (int fm = 0; fm < 4; ++fm)
#pragma unroll
        for (int fn = 0; fn < 4; ++fn)
          acc[fm][fn] = __builtin_amdgcn_mfma_f32_16x16x32_bf16(
              a[fm], bb[fn], acc[fm][fn], 0, 0, 0);
    }
  }

  const float sc = (z == 0) ? EXPC : 1.0f;
#pragma unroll
  for (int fn = 0; fn < 4; ++fn) {
    int col = col0 + wn * 64 + fn * 16 + lr;
    float bv = bias[col];
#pragma unroll
    for (int fm = 0; fm < 4; ++fm) {
      int row = row0 + wm * 64 + fm * 16 + lk * 4;
      if (z == 2) {
        int b_ = row >> 11, s = row & 2047;
        int hh = col >> 6, d = col & 63;
        ushortx4 o4 = {f2bf(acc[fm][fn][0] + bv), f2bf(acc[fm][fn][1] + bv),
                       f2bf(acc[fm][fn][2] + bv), f2bf(acc[fm][fn][3] + bv)};
        *(ushortx4*)(Out + ((size_t)(b_ * HEADS + hh) * HDIM + d) * SEQ + s) = o4;
      } else {
#pragma unroll
        for (int r = 0; r < 4; ++r)
          Out[(size_t)(row + r) * HID + col] = f2bf((acc[fm][fn][r] + bv) * sc);
      }
    }
  }
}

// ---------------- Wo GEMM ----------------
// Flat grid 512, XCD-chunked swizzle. W_F32: fp32 W fallback.
template <int W_F32>
__global__ __launch_bounds__(256) void gemm_wo(
    const unsigned short* __restrict__ A, const void* __restrict__ Wp,
    const float* __restrict__ bias, float* __restrict__ Out) {
  __shared__ unsigned short Als[128 * 64];
  __shared__ unsigned short Bls[128 * 64];
  const int bid = blockIdx.x;
  const int wgid = (bid & 7) * 64 + (bid >> 3);
  const int bm = wgid >> 3, bn = wgid & 7;
  const int t = threadIdx.x;
  const int w = t >> 6, lane = t & 63;
  const int wm = w >> 1, wn = w & 1;
  const int lr = lane & 15, lk = lane >> 4;
  const int row0 = bm * 128, col0 = bn * 128;

  const unsigned short* Abase =
      A + (size_t)(row0 + w * 32 + (lane >> 3)) * HID + (lane & 7) * 8;
  const unsigned short* Wb16 =
      (const unsigned short*)Wp + (size_t)(col0 + w * 32 + (lane >> 3)) * HID +
      (lane & 7) * 8;

  f32x4 acc[4][4] = {};

  for (int ks = 0; ks < 16; ++ks) {
    __syncthreads();
#pragma unroll
    for (int i = 0; i < 4; ++i)
      gl16(Abase + (size_t)i * 8 * HID + ks * 64, &Als[(w * 32 + i * 8) * 64]);
    if (!W_F32) {
#pragma unroll
      for (int i = 0; i < 4; ++i)
        gl16(Wb16 + (size_t)i * 8 * HID + ks * 64, &Bls[(w * 32 + i * 8) * 64]);
    } else {
      const float* Wf = (const float*)Wp;
#pragma unroll
      for (int i = 0; i < 8; ++i) {
        int chunk = t + i * 256;
        int r = chunk >> 4, c4 = (chunk & 15) * 4;
        float4 v4 = *(const float4*)(Wf + (size_t)(col0 + r) * HID + ks * 64 + c4);
        ushortx4 o = {f2bf(v4.x), f2bf(v4.y), f2bf(v4.z), f2bf(v4.w)};
        *(ushortx4*)&Bls[r * 64 + c4] = o;
      }
    }
    __syncthreads();
#pragma unroll
    for (int kk = 0; kk < 2; ++kk) {
      bf16x8 a[4], bb[4];
#pragma unroll
      for (int f = 0; f < 4; ++f) {
        a[f] = *(const bf16x8*)&Als[(wm * 64 + f * 16 + lr) * 64 + kk * 32 + lk * 8];
        bb[f] = *(const bf16x8*)&Bls[(wn * 64 + f * 16 + lr) * 64 + kk * 32 + lk * 8];
      }
#pragma unroll
      for (int fm = 0; fm < 4; ++fm)
#pragma unroll
        for (int fn = 0; fn < 4; ++fn)
          acc[fm][fn] = __builtin_amdgcn_mfma_f32_16x16x32_bf16(
              a[fm], bb[fn], acc[fm][fn], 0, 0, 0);
    }
  }

#pragma unroll
  for (int fn = 0; fn < 4; ++fn) {
    int col = col0 + wn * 64 + fn * 16 + lr;
    float bv = bias[col];
#pragma unroll
    for (int fm = 0; fm < 4; ++fm) {
      int row = row0 + wm * 64 + fm * 16 + lk * 4;
#pragma unroll
      for (int r = 0; r < 4; ++r)
        Out[(size_t)(row + r) * HID + col] = acc[fm][fn][r] + bv;
    }
  }
}

// ---------------- attention ----------------
// Best-known config (402 us, Round-6 bench). Flat grid 512 (all-resident),
// XCD-chunked swizzle; each block does 2 q-blocks of 128 rows sequentially
// (same h,b). Two-pass per q-block, no max-tracking; Q pre-scaled by EXPC.
// K/V via global_load_lds, XOR-swizzled via source, double-buffered, one
// barrier per tile. NT f32x4 attn stores; ushortx4 P reads. NO min-waves pin
// (pin + this body regressed in R8-R10 probes).
__global__ __launch_bounds__(512) void attn_kern(
    const unsigned short* __restrict__ Qb, const unsigned short* __restrict__ Kb,
    const unsigned short* __restrict__ Vt, float* __restrict__ attn_out,
    unsigned short* __restrict__ Xc) {
  __shared__ unsigned short Qls[128][72];  // reused as P (bf16) in pass 2
  __shared__ unsigned short Kls[2][64 * 64];
  __shared__ unsigned short Vls[2][64 * 64];

  const int t = threadIdx.x;
  const int bid = blockIdx.x;
  const int wgid = (bid & 7) * 64 + (bid >> 3);
  const int qbp = wgid & 7;
  const int h = (wgid >> 3) & 15;
  const int b = wgid >> 7;

  const int w = t >> 6, lane = t & 63;
  const int lr = lane & 15, lk = lane >> 4;

  const int srow = lane >> 3;
  const int scol = (lane & 7) ^ srow;
  const unsigned short* gK =
      Kb + ((size_t)b * SEQ + w * 8 + srow) * HID + h * HDIM + scol * 8;
  const unsigned short* gV =
      Vt + ((size_t)(b * HEADS + h) * HDIM + w * 8 + srow) * SEQ + scol * 8;
  unsigned short* lK = &Kls[0][w * 8 * 64];  // +4096 for buf 1
  unsigned short* lV = &Vls[0][w * 8 * 64];

  for (int qbi = 0; qbi < 2; ++qbi) {
    const int qb = qbp * 2 + qbi;
    const size_t qrow0 = (size_t)b * SEQ + (size_t)qb * 128;

    gl16(gK, lK);
#pragma unroll
    for (int i = 0; i < 2; ++i) {
      int chunk = t + i * 512;
      int r = chunk >> 3, c8 = (chunk & 7) * 8;
      *(ushortx8*)&Qls[r][c8] =
          *(const ushortx8*)(Qb + (qrow0 + r) * HID + h * HDIM + c8);
    }
    __syncthreads();

    bf16x8 qf[2];
#pragma unroll
    for (int kk = 0; kk < 2; ++kk)
      qf[kk] = *(const bf16x8*)&Qls[w * 16 + lr][kk * 32 + lk * 8];
    auto& Pls = Qls;

    float lsum[4] = {0.f, 0.f, 0.f, 0.f};
    int buf = 0;

    // ---- pass 1: row sums of exp2 ----
    for (int kt = 0; kt < 32; ++kt) {
      if (kt < 31) gl16(gK + (size_t)(kt + 1) * 64 * HID, lK + (buf ^ 1) * 4096);
      f32x4 acc[4] = {};
      __builtin_amdgcn_s_setprio(1);
#pragma unroll
      for (int kk = 0; kk < 2; ++kk)
#pragma unroll
        for (int kf = 0; kf < 4; ++kf) {
          bf16x8 bb = *(const bf16x8*)&Kls[buf][(kf * 16 + lr) * 64 +
                                               (((kk * 4 + lk) ^ (lr & 7)) << 3)];
          acc[kf] =
              __builtin_amdgcn_mfma_f32_16x16x32_bf16(qf[kk], bb, acc[kf], 0, 0, 0);
        }
      __builtin_amdgcn_s_setprio(0);
#pragma unroll
      for (int kf = 0; kf < 4; ++kf)
#pragma unroll
        for (int r = 0; r < 4; ++r) lsum[r] += exp2f(acc[kf][r]);
      __syncthreads();
      buf ^= 1;
    }

    float invl[4];
#pragma unroll
    for (int r = 0; r < 4; ++r) {
#pragma unroll
      for (int off = 1; off < 16; off <<= 1) lsum[r] += __shfl_xor(lsum[r], off, 64);
      invl[r] = 1.0f / lsum[r];
    }

    f32x4 oacc[4] = {};
    float* attn_base =
        attn_out + ((size_t)(b * HEADS + h) * SEQ + (size_t)qb * 128) * SEQ;

    // ---- pass 2 ---- (buf is 0 again)
    gl16(gK, lK);
    gl16(gV, lV);
    __syncthreads();
    for (int kt = 0; kt < 32; ++kt) {
      if (kt < 31) {
        gl16(gK + (size_t)(kt + 1) * 64 * HID, lK + (buf ^ 1) * 4096);
        gl16(gV + (size_t)(kt + 1) * 64, lV + (buf ^ 1) * 4096);
      }
      f32x4 acc[4] = {};
      __builtin_amdgcn_s_setprio(1);
#pragma unroll
      for (int kk = 0; kk < 2; ++kk)
#pragma unroll
        for (int kf = 0; kf < 4; ++kf) {
          bf16x8 bb = *(const bf16x8*)&Kls[buf][(kf * 16 + lr) * 64 +
                                               (((kk * 4 + lk) ^ (lr & 7)) << 3)];
          acc[kf] =
              __builtin_amdgcn_mfma_f32_16x16x32_bf16(qf[kk], bb, acc[kf], 0, 0, 0);
        }
      __builtin_amdgcn_s_setprio(0);
#pragma unroll
      for (int kf = 0; kf < 4; ++kf)
#pragma unroll
        for (int r = 0; r < 4; ++r) {
          float p = exp2f(acc[kf][r]) * invl[r];
          Pls[w * 16 + lk * 4 + r][kf * 16 + lr] = f2bf(p);
        }
#pragma unroll
      for (int it = 0; it < 4; ++it) {
        int rl = it * 4 + lk;
        ushortx4 p4 = *(const ushortx4*)&Pls[w * 16 + rl][lr * 4];
        f32x4 o = {bf2f(p4[0]), bf2f(p4[1]), bf2f(p4[2]), bf2f(p4[3])};
        __builtin_nontemporal_store(
            o, (f32x4*)(attn_base + (size_t)(w * 16 + rl) * SEQ + kt * 64 + lr * 4));
      }
      __builtin_amdgcn_s_setprio(1);
#pragma unroll
      for (int kk = 0; kk < 2; ++kk) {
        bf16x8 ap = *(const bf16x8*)&Pls[w * 16 + lr][kk * 32 + lk * 8];
#pragma unroll
        for (int df = 0; df < 4; ++df) {
          bf16x8 bv = *(const bf16x8*)&Vls[buf][(df * 16 + lr) * 64 +
                                               (((kk * 4 + lk) ^ (lr & 7)) << 3)];
          oacc[df] = __builtin_amdgcn_mfma_f32_16x16x32_bf16(ap, bv, oacc[df], 0, 0, 0);
        }
      }
      __builtin_amdgcn_s_setprio(0);
      __syncthreads();
      buf ^= 1;
    }

#pragma unroll
    for (int df = 0; df < 4; ++df)
#pragma unroll
      for (int r = 0; r < 4; ++r) {
        int row = w * 16 + lk * 4 + r;
        int col = h * HDIM + df * 16 + lr;
        Xc[(qrow0 + row) * HID + col] = f2bf(oacc[df][r]);
      }
  }
}

extern "C" void kernel_launch(void* const* d_in, const int* in_sizes, int n_in,
                              void* d_out, int out_size, void* d_ws, size_t ws_size,
                              hipStream_t stream) {
  const float* q = (const float*)d_in[0];
  const float* k = (const float*)d_in[1];
  const float* v = (const float*)d_in[2];
  const float* Wq = (const float*)d_in[3];
  const float* bq = (const float*)d_in[4];
  const float* Wk = (const float*)d_in[5];
  const float* bk = (const float*)d_in[6];
  const float* Wv = (const float*)d_in[7];
  const float* bv = (const float*)d_in[8];
  const float* Wo = (const float*)d_in[9];
  const float* bo = (const float*)d_in[10];

  char* ws = (char*)d_ws;
  const size_t MAT = (size_t)8192 * 1024 * sizeof(unsigned short);  // 16 MiB
  unsigned short* Qbuf = (unsigned short*)(ws);
  unsigned short* Kbuf = (unsigned short*)(ws + MAT);
  unsigned short* Vtb = (unsigned short*)(ws + 2 * MAT);
  unsigned short* Xc = (unsigned short*)(ws + 3 * MAT);

  float* xout = (float*)d_out;
  float* attn_out = xout + (size_t)BATCH * SEQ * HID;

  // bf16 weight copies for Wq/Wk/Wv live in the attn region of d_out
  // (fully overwritten later by attn_kern; consumed before that).
  unsigned short* scr = (unsigned short*)attn_out;
  const int NW = 1024 * 1024;
  unsigned short* wq16 = scr;
  unsigned short* wk16 = wq16 + NW;
  unsigned short* wv16 = wk16 + NW;
  // Wo bf16 copy must survive attn -> lives in ws (guarded by ws_size)
  unsigned short* wo16 = (unsigned short*)(ws + 4 * MAT);
  const bool wo_bf = ws_size >= 4 * MAT + (size_t)NW * sizeof(unsigned short);

  ConvArgs ca;
  ca.s[0] = Wq; ca.s[1] = Wk; ca.s[2] = Wv; ca.s[3] = Wo;
  ca.d[0] = wq16; ca.d[1] = wk16; ca.d[2] = wv16; ca.d[3] = wo16;
  ca.n[0] = NW; ca.n[1] = NW; ca.n[2] = NW; ca.n[3] = NW;

  dim3 blk(256);
  hipLaunchKernelGGL(convk, dim3(128, wo_bf ? 4 : 3), blk, 0, stream, ca);

  QkvArgs qa;
  qa.Af[0] = q; qa.Af[1] = k; qa.Af[2] = v;
  qa.W[0] = wq16; qa.W[1] = wk16; qa.W[2] = wv16;
  qa.bias[0] = bq; qa.bias[1] = bk; qa.bias[2] = bv;
  qa.out[0] = Qbuf; qa.out[1] = Kbuf; qa.out[2] = Vtb;
  hipLaunchKernelGGL(gemm_qkv, dim3(1536), blk, 0, stream, qa);

  hipLaunchKernelGGL(attn_kern, dim3(512), dim3(512), 0, stream, Qbuf, Kbuf, Vtb,
                     attn_out, Xc);

  if (wo_bf)
    hipLaunchKernelGGL((gemm_wo<0>), dim3(512), blk, 0, stream, Xc, wo16, bo, xout);
  else
    hipLaunchKernelGGL((gemm_wo<1>), dim3(512), blk, 0, stream, Xc, Wo, bo, xout);
}